// Round 9
// baseline (290.615 us; speedup 1.0000x reference)
//
#include <hip/hip_runtime.h>
#include <hip/hip_bf16.h>

typedef float f32x4 __attribute__((ext_vector_type(4)));
typedef float f32x16 __attribute__((ext_vector_type(16)));
typedef short s16x8 __attribute__((ext_vector_type(8)));
typedef short s16x4 __attribute__((ext_vector_type(4)));

__device__ __forceinline__ short f2bf(float f) {
  union { float f; unsigned u; } v; v.f = f;
  unsigned r = v.u + 0x7fffu + ((v.u >> 16) & 1u);
  return (short)(r >> 16);
}
__device__ __forceinline__ float bf2f(short s) {
  union { unsigned u; float f; } v; v.u = ((unsigned)(unsigned short)s) << 16;
  return v.f;
}
__device__ __forceinline__ unsigned cvtpk(float lo, float hi) {
  unsigned r;
  asm("v_cvt_pk_bf16_f32 %0, %1, %2" : "=v"(r) : "v"(lo), "v"(hi));
  return r;
}

__device__ __forceinline__ void gload_lds16(const short* g, short* l) {
  __builtin_amdgcn_global_load_lds(
      (const __attribute__((address_space(1))) void*)g,
      (__attribute__((address_space(3))) void*)l, 16, 0, 0);
}

// ---------------- fp32 -> bf16 convert (8 elems/thread) ----------------
__global__ __launch_bounds__(256) void k_f2bf(const float* __restrict__ in,
                                              short* __restrict__ out, int n8) {
  int i = blockIdx.x * 256 + threadIdx.x;
  if (i >= n8) return;
  const float4* p = (const float4*)in + (size_t)i * 2;
  float4 a = p[0], b = p[1];
  s16x8 o;
  o[0] = f2bf(a.x); o[1] = f2bf(a.y); o[2] = f2bf(a.z); o[3] = f2bf(a.w);
  o[4] = f2bf(b.x); o[5] = f2bf(b.y); o[6] = f2bf(b.z); o[7] = f2bf(b.w);
  *(s16x8*)(out + (size_t)i * 8) = o;
}

// ---------- merged weight convert: Wq|Wk|Wv -> wqkv, Wo -> wo ----------
__global__ __launch_bounds__(256) void k_f2bfw(const float* __restrict__ s0,
                                               const float* __restrict__ s1,
                                               const float* __restrict__ s2,
                                               const float* __restrict__ s3,
                                               short* __restrict__ dqkv,
                                               short* __restrict__ dwo) {
  int i = blockIdx.x * 256 + threadIdx.x;  // total n8 = 1310720
  const float* src;
  short* dst;
  if (i < 524288) { src = s0 + (size_t)i * 8; dst = dqkv + (size_t)i * 8; }
  else if (i < 655360) { int j = i - 524288; src = s1 + (size_t)j * 8; dst = dqkv + 4194304 + (size_t)j * 8; }
  else if (i < 786432) { int j = i - 655360; src = s2 + (size_t)j * 8; dst = dqkv + 5242880 + (size_t)j * 8; }
  else { int j = i - 786432; src = s3 + (size_t)j * 8; dst = dwo + (size_t)j * 8; }
  const float4* p = (const float4*)src;
  float4 a = p[0], b = p[1];
  s16x8 o;
  o[0] = f2bf(a.x); o[1] = f2bf(a.y); o[2] = f2bf(a.z); o[3] = f2bf(a.w);
  o[4] = f2bf(b.x); o[5] = f2bf(b.y); o[6] = f2bf(b.z); o[7] = f2bf(b.w);
  *(s16x8*)dst = o;
}

// ---------------- bf16 GEMM: C[M,N] = A[M,K] @ Bw[N,K]^T ----------------
// MODE 1: fp32 row-major C.  MODE 3: fused QKV epilogue.
// XCD-aware bijective block swizzle (T1); requires nwg % 8 == 0.
template <int MODE>
__global__ __launch_bounds__(256) void k_gemm_bt(const short* __restrict__ A,
                                                 const short* __restrict__ Bw,
                                                 void* __restrict__ C,
                                                 void* __restrict__ C2,
                                                 void* __restrict__ C3,
                                                 int M, int N, int K) {
  __shared__ __align__(16) short As[128 * 64];
  __shared__ __align__(16) short Bs[128 * 64];
  const int tid = threadIdx.x;
  const int w = tid >> 6, lane = tid & 63;
  const int wm = w >> 1, wn = w & 1;
  const int nbx = gridDim.x;
  const int f = blockIdx.y * nbx + blockIdx.x;
  const int cpx = (nbx * gridDim.y) >> 3;
  const int sw = (f & 7) * cpx + (f >> 3);
  const int bm = sw / nbx, bn = sw % nbx;
  const int l15 = lane & 15, l4 = lane >> 4;

  f32x4 acc[4][4] = {};

  const int nk = K >> 6;
  for (int kt = 0; kt < nk; ++kt) {
    __syncthreads();
#pragma unroll
    for (int it = 0; it < 4; ++it) {
      int p = it * 256 + tid;
      int p0 = it * 256 + w * 64;
      int r = p >> 3, j = p & 7;
      int jsrc = j ^ (r & 7);
      gload_lds16(A + (size_t)(bm * 128 + r) * K + kt * 64 + jsrc * 8, &As[p0 * 8]);
      gload_lds16(Bw + (size_t)(bn * 128 + r) * K + kt * 64 + jsrc * 8, &Bs[p0 * 8]);
    }
    __syncthreads();
#pragma unroll
    for (int kk = 0; kk < 2; ++kk) {
      s16x8 af[4], bf[4];
      const int jj = kk * 4 + l4;
#pragma unroll
      for (int mi = 0; mi < 4; ++mi) {
        int r = wm * 64 + mi * 16 + l15;
        af[mi] = *(const s16x8*)&As[(r * 8 + (jj ^ (r & 7))) * 8];
      }
#pragma unroll
      for (int ni = 0; ni < 4; ++ni) {
        int r = wn * 64 + ni * 16 + l15;
        bf[ni] = *(const s16x8*)&Bs[(r * 8 + (jj ^ (r & 7))) * 8];
      }
      __builtin_amdgcn_s_setprio(1);
#pragma unroll
      for (int mi = 0; mi < 4; ++mi)
#pragma unroll
        for (int ni = 0; ni < 4; ++ni)
          acc[mi][ni] = __builtin_amdgcn_mfma_f32_16x16x32_bf16(
              af[mi], bf[ni], acc[mi][ni], 0, 0, 0);
      __builtin_amdgcn_s_setprio(0);
    }
  }

#pragma unroll
  for (int mi = 0; mi < 4; ++mi) {
#pragma unroll
    for (int ni = 0; ni < 4; ++ni) {
      int row0 = bm * 128 + wm * 64 + mi * 16 + l4 * 4;
      int col = bn * 128 + wn * 64 + ni * 16 + l15;
      if (MODE == 1) {
        float* Cf = (float*)C;
#pragma unroll
        for (int r2 = 0; r2 < 4; ++r2)
          Cf[(size_t)(row0 + r2) * N + col] = acc[mi][ni][r2];
      } else {  // MODE 3: fused QKV
        if (col < 2048) {
          short* Qo = (short*)C;
#pragma unroll
          for (int r2 = 0; r2 < 4; ++r2)
            Qo[(size_t)(row0 + r2) * 2048 + col] = f2bf(acc[mi][ni][r2]);
        } else if (col < 2560) {
          short* Ko = (short*)C2;
#pragma unroll
          for (int r2 = 0; r2 < 4; ++r2)
            Ko[(size_t)(row0 + r2) * 512 + (col - 2048)] = f2bf(acc[mi][ni][r2]);
        } else {
          short* Vo = (short*)C3;
          int b = row0 >> 11, t0 = row0 & 2047;
          s16x4 pk;
#pragma unroll
          for (int r2 = 0; r2 < 4; ++r2) pk[r2] = f2bf(acc[mi][ni][r2]);
          *(s16x4*)&Vo[(size_t)b * 1048576 + (size_t)(col - 2560) * 2048 + t0] = pk;
        }
      }
    }
  }
}

// ---------------- RoPE in-place on bf16 K ----------------
__global__ __launch_bounds__(256) void k_rope(short* __restrict__ X, int shift,
                                              int rowstride, float mul) {
  int idx = blockIdx.x * 256 + threadIdx.x;
  int row = idx >> shift;
  int rem = idx & ((1 << shift) - 1);
  int h = rem >> 6, d = rem & 63;
  int t = row & 2047;
  float inv = exp2f(-(float)d * (13.287712379549449f / 64.f));
  float ang = (float)t * inv;
  float s, c;
  sincosf(ang, &s, &c);
  size_t base = (size_t)row * rowstride + h * 128 + d;
  float q0 = bf2f(X[base]), q1 = bf2f(X[base + 64]);
  X[base] = f2bf((q0 * c - q1 * s) * mul);
  X[base + 64] = f2bf((q1 * c + q0 * s) * mul);
}

// ---------------- queue counter zero ----------------
__global__ void k_zero(int* p) { if (threadIdx.x == 0) *p = 0; }

// ---------------- flash attention, work-stealing 64-row items ------------
// Round-5 inner loop (best measured) + 48KB LDS (V single-buffered via
// reg-staging, r4 mapping) -> 3 blocks/CU; grid 768; no min-wave bound.
__global__ __launch_bounds__(256) void k_attn8(const short* __restrict__ Q,
                                               const short* __restrict__ Kb,
                                               const short* __restrict__ Vt,
                                               short* __restrict__ Y,
                                               int* __restrict__ qcnt) {
  __shared__ __align__(16) char smem[49152];  // Ks[2][64*128] | Vs[128*64]
  __shared__ int s_item;
  short* Ks0 = (short*)smem;                  // 16 KB
  short* Ks1 = (short*)(smem + 16384);        // 16 KB
  short* Vs  = (short*)(smem + 32768);        // 16 KB
  float* mg0 = (float*)smem;                  // merge overlay: 17408 B
  float* mg1 = (float*)(smem + 17408);        // merge overlay: 17408 B

  const int tid = threadIdx.x;
  const int w = tid >> 6, lane = tid & 63;
  const int l31 = lane & 31, h5 = lane >> 5;
  const int qc0 = (w >> 1) << 5;  // q-col block: 0 or 32
  const int par = w & 1;          // kv subtile parity
  const int vr0 = tid >> 3, vc0 = tid & 7;
  const int vslot = (vc0 + vr0) & 7;

  for (;;) {
    if (tid == 0) s_item = atomicAdd(qcnt, 1);
    __syncthreads();  // broadcast + protects LDS reuse across items
    const int item = s_item;
    if (item >= 1024) return;
    const int qi = 31 - (item >> 5);
    const int h = (item >> 1) & 15;
    const int b = item & 1;
    const int kh = h >> 2;
    const int q0 = qi << 6;

    // Q fragments (B-operand): lane = q-col l31, frag f covers d=f*16+h5*8
    s16x8 qf[8];
    const size_t qrow = (size_t)(b * 2048 + q0 + qc0 + l31);
#pragma unroll
    for (int f = 0; f < 8; ++f)
      qf[f] = *(const s16x8*)(Q + qrow * 2048 + h * 128 + f * 16 + h5 * 8);

    // RoPE + softmax scale folded in-register: pair (d, d+64) = qf[f], qf[f+4]
    {
      const float tpos = (float)(q0 + qc0 + l31);
#pragma unroll
      for (int f = 0; f < 4; ++f) {
#pragma unroll
        for (int e = 0; e < 8; ++e) {
          int d = f * 16 + h5 * 8 + e;
          float inv = exp2f((float)d * (-13.287712379549449f / 64.f));
          float sn, cs;
          __sincosf(tpos * inv, &sn, &cs);
          float a = bf2f(qf[f][e]), bv = bf2f(qf[f + 4][e]);
          qf[f][e]     = f2bf((a * cs - bv * sn) * 0.12751758912141852f);
          qf[f + 4][e] = f2bf((bv * cs + a * sn) * 0.12751758912141852f);
        }
      }
    }

    f32x16 oacc[4] = {};
    float m = -1e30f, l = 0.f;

    auto stageK = [&](short* buf, int t) {
#pragma unroll
      for (int it = 0; it < 4; ++it) {  // K pair: 64 rows x 16 chunks
        int p = it * 256 + tid;
        int p0 = it * 256 + w * 64;
        int r = p >> 4, c = p & 15;
        int csrc = (c - r) & 15;
        gload_lds16(Kb + (size_t)(b * 2048 + t * 64 + r) * 512 + kh * 128 + csrc * 8,
                    &buf[p0 * 8]);
      }
    };

    // V reg-staging: global -> vreg (issue with K prefetch), vreg -> LDS
    // after the barrier. Row r = q*32+vr0, chunk vc0, rotated slot vslot.
    uint4 vreg[4];
    auto vload = [&](int t) {
#pragma unroll
      for (int q = 0; q < 4; ++q) {
        int r = q * 32 + vr0;
        vreg[q] = *(const uint4*)(Vt + (size_t)b * 1048576 +
                                  (size_t)(kh * 128 + r) * 2048 + t * 64 + vc0 * 8);
      }
    };
    auto vwrite = [&]() {
#pragma unroll
      for (int q = 0; q < 4; ++q) {
        int r = q * 32 + vr0;
        *(uint4*)&Vs[(r * 8 + vslot) * 8] = vreg[q];
      }
    };

    stageK(Ks0, 0);
    vload(0);
    __syncthreads();  // drain K staging + vreg loads
    vwrite();
    __syncthreads();  // Vs(0) visible

    for (int t = 0; t <= qi; ++t) {
      short* Kcur = (t & 1) ? Ks1 : Ks0;
      short* Knxt = (t & 1) ? Ks0 : Ks1;
      if (t < qi) { stageK(Knxt, t + 1); vload(t + 1); }

      const bool skipw = (t == qi) && (w == 1);
      if (!skipw) {
        // ---- S^T = K_sub @ Q (kf reads interleaved, as round 5) ----
        f32x16 sa = {};
        const int kr = par * 32 + l31;
        __builtin_amdgcn_s_setprio(1);
#pragma unroll
        for (int f = 0; f < 8; ++f) {
          int c = f * 2 + h5;
          s16x8 kf = *(const s16x8*)&Kcur[(kr * 16 + ((c + kr) & 15)) * 8];
          sa = __builtin_amdgcn_mfma_f32_32x32x16_bf16(kf, qf[f], sa, 0, 0, 0);
        }
        __builtin_amdgcn_s_setprio(0);

        if (t == qi && (w == 0 || w == 3)) {  // diagonal subtile mask
#pragma unroll
          for (int rg = 0; rg < 16; ++rg) {
            int krow = (rg & 3) + 8 * (rg >> 2) + 4 * h5;
            if (krow > l31) sa[rg] = -3.0e38f;
          }
        }

        // ---- online softmax (exp2 domain) ----
        float mx[16];
#pragma unroll
        for (int i = 0; i < 16; ++i) mx[i] = sa[i];
#pragma unroll
        for (int stp = 8; stp > 0; stp >>= 1)
#pragma unroll
          for (int i = 0; i < stp; ++i) mx[i] = fmaxf(mx[i], mx[i + stp]);
        float pm = fmaxf(mx[0], __shfl_xor(mx[0], 32));

        if (!__all(pm - m <= 8.f)) {  // defer-max (T13)
          float mn = fmaxf(m, pm);
          float al = exp2f(m - mn);
          m = mn;
          l *= al;
#pragma unroll
          for (int d = 0; d < 4; ++d)
#pragma unroll
            for (int i = 0; i < 16; ++i) oacc[d][i] *= al;
        }

        float sm[16];
#pragma unroll
        for (int i = 0; i < 16; ++i) {
          float e = exp2f(sa[i] - m);
          sa[i] = e;
          sm[i] = e;
        }
#pragma unroll
        for (int stp = 8; stp > 0; stp >>= 1)
#pragma unroll
          for (int i = 0; i < stp; ++i) sm[i] += sm[i + stp];
        l += sm[0] + __shfl_xor(sm[0], 32);

        // ---- P -> bf16 B-operand fragments (in-register relayout) ----
        unsigned u[8], pu[8];
#pragma unroll
        for (int g = 0; g < 4; ++g) {
          u[2 * g]     = cvtpk(sa[4 * g + 0], sa[4 * g + 1]);
          u[2 * g + 1] = cvtpk(sa[4 * g + 2], sa[4 * g + 3]);
        }
#pragma unroll
        for (int g2 = 0; g2 < 8; ++g2) pu[g2] = __shfl_xor(u[g2], 32);
        s16x8 pb[2];
#pragma unroll
        for (int kk = 0; kk < 2; ++kk) {
          union { unsigned uu[4]; s16x8 v; } cv;
          cv.uu[0] = h5 ? pu[4 * kk + 2] : u[4 * kk];
          cv.uu[1] = h5 ? pu[4 * kk + 3] : u[4 * kk + 1];
          cv.uu[2] = h5 ? u[4 * kk + 2]  : pu[4 * kk];
          cv.uu[3] = h5 ? u[4 * kk + 3]  : pu[4 * kk + 1];
          pb[kk] = cv.v;
        }

        // ---- O^T += V_sub^T @ P^T (vf read at PV site, as round 5) ----
        __builtin_amdgcn_s_setprio(1);
#pragma unroll
        for (int dblk = 0; dblk < 4; ++dblk)
#pragma unroll
          for (int kk = 0; kk < 2; ++kk) {
            int r = dblk * 32 + l31;
            int c = par * 4 + kk * 2 + h5;
            s16x8 vfr = *(const s16x8*)&Vs[(r * 8 + ((c + r) & 7)) * 8];
            oacc[dblk] = __builtin_amdgcn_mfma_f32_32x32x16_bf16(
                vfr, pb[kk], oacc[dblk], 0, 0, 0);
          }
        __builtin_amdgcn_s_setprio(0);
      }

      __syncthreads();  // drains prefetch (K lds + vreg); Vs free
      if (t < qi) {
        vwrite();
        __syncthreads();  // Vs(t+1) visible
      }
    }

    // ---- merge parity partials: odd wave writes, even wave merges+stores --
    const int base = (h5 * 32 + l31) * 68;  // 68-float stride
    if (par) {
      float* mg = (w == 1) ? mg0 : mg1;
#pragma unroll
      for (int d = 0; d < 4; ++d)
#pragma unroll
        for (int rg = 0; rg < 4; ++rg) {
          f32x4 tv;
          tv[0] = oacc[d][rg * 4 + 0];
          tv[1] = oacc[d][rg * 4 + 1];
          tv[2] = oacc[d][rg * 4 + 2];
          tv[3] = oacc[d][rg * 4 + 3];
          *(f32x4*)&mg[base + d * 16 + rg * 4] = tv;
        }
      mg[base + 64] = m;
      mg[base + 65] = l;
    }
    __syncthreads();
    if (!par) {
      const float* mg = (w == 0) ? mg0 : mg1;
      float m1 = mg[base + 64], l1 = mg[base + 65];
      float ms = fmaxf(m, m1);
      float a0 = exp2f(m - ms), a1 = exp2f(m1 - ms);
      float li = 1.f / (l * a0 + l1 * a1);
#pragma unroll
      for (int d = 0; d < 4; ++d) {
#pragma unroll
        for (int rg = 0; rg < 4; ++rg) {
          f32x4 po = *(const f32x4*)&mg[base + d * 16 + rg * 4];
          float v0 = (oacc[d][rg * 4 + 0] * a0 + po[0] * a1) * li;
          float v1 = (oacc[d][rg * 4 + 1] * a0 + po[1] * a1) * li;
          float v2 = (oacc[d][rg * 4 + 2] * a0 + po[2] * a1) * li;
          float v3 = (oacc[d][rg * 4 + 3] * a0 + po[3] * a1) * li;
          uint2 st;
          st.x = cvtpk(v0, v1);
          st.y = cvtpk(v2, v3);
          int d0 = d * 32 + 8 * rg + 4 * h5;
          *(uint2*)(Y + qrow * 2048 + h * 128 + d0) = st;
        }
      }
    }
    // next pop's __syncthreads() protects merge buffers before restaging
  }
}

extern "C" void kernel_launch(void* const* d_in, const int* in_sizes, int n_in,
                              void* d_out, int out_size, void* d_ws, size_t ws_size,
                              hipStream_t stream) {
  (void)in_sizes; (void)n_in; (void)out_size; (void)ws_size;
  const float* x  = (const float*)d_in[0];
  const float* Wq = (const float*)d_in[1];
  const float* Wk = (const float*)d_in[2];
  const float* Wv = (const float*)d_in[3];
  const float* Wo = (const float*)d_in[4];

  char* ws = (char*)d_ws;
  short* xb    = (short*)(ws);              // 4096x2048 bf16 (16 MiB)
  short* wqkvb = (short*)(ws + 16777216);   // 3072x2048      (12 MiB)
  short* wob   = (short*)(ws + 29360128);   // 2048x2048      (8 MiB)
  short* Qb    = (short*)(ws + 37748736);   // 4096x2048      (16 MiB)
  short* Kb    = (short*)(ws + 54525952);   // 4096x512       (4 MiB)
  short* Vtb   = (short*)(ws + 58720256);   // 2x512x2048     (4 MiB)
  short* Yb    = (short*)(ws + 62914560);   // 4096x2048      (16 MiB)
  // queue counter: last 64B of wqkvb (dead after QKV GEMM, rewritten each call)
  int* qcnt    = (int*)(ws + 29360128 - 64);

  k_f2bf<<<4096, 256, 0, stream>>>(x, xb, 1048576);
  k_f2bfw<<<5120, 256, 0, stream>>>(Wq, Wk, Wv, Wo, wqkvb, wob);

  // fused QKV projection: N = 2048(Q) + 512(K) + 512(V) = 3072
  k_gemm_bt<3><<<dim3(24, 32), 256, 0, stream>>>(xb, wqkvb, Qb, Kb, Vtb,
                                                 4096, 3072, 2048);

  // K RoPE only; Q RoPE (+ log2(e)/sqrt(128) scale) is folded into k_attn8
  k_rope<<<4096, 256, 0, stream>>>(Kb, 8, 512, 1.0f);

  k_zero<<<1, 64, 0, stream>>>(qcnt);  // after QKV GEMM consumed wqkvb
  k_attn8<<<768, 256, 0, stream>>>(Qb, Kb, Vtb, Yb, qcnt);

  k_gemm_bt<1><<<dim3(16, 32), 256, 0, stream>>>(Yb, wob, d_out, nullptr,
                                                 nullptr, 4096, 2048, 2048);
}

// Round 10
// 193.700 us; speedup vs baseline: 1.5003x; 1.5003x over previous
//
#include <hip/hip_runtime.h>
#include <hip/hip_bf16.h>

typedef float f32x4 __attribute__((ext_vector_type(4)));
typedef float f32x16 __attribute__((ext_vector_type(16)));
typedef short s16x8 __attribute__((ext_vector_type(8)));
typedef short s16x4 __attribute__((ext_vector_type(4)));

__device__ __forceinline__ short f2bf(float f) {
  union { float f; unsigned u; } v; v.f = f;
  unsigned r = v.u + 0x7fffu + ((v.u >> 16) & 1u);
  return (short)(r >> 16);
}
__device__ __forceinline__ float bf2f(short s) {
  union { unsigned u; float f; } v; v.u = ((unsigned)(unsigned short)s) << 16;
  return v.f;
}
__device__ __forceinline__ unsigned cvtpk(float lo, float hi) {
  unsigned r;
  asm("v_cvt_pk_bf16_f32 %0, %1, %2" : "=v"(r) : "v"(lo), "v"(hi));
  return r;
}

__device__ __forceinline__ void gload_lds16(const short* g, short* l) {
  __builtin_amdgcn_global_load_lds(
      (const __attribute__((address_space(1))) void*)g,
      (__attribute__((address_space(3))) void*)l, 16, 0, 0);
}

// ---------------- fp32 -> bf16 convert (8 elems/thread) ----------------
__global__ __launch_bounds__(256) void k_f2bf(const float* __restrict__ in,
                                              short* __restrict__ out, int n8) {
  int i = blockIdx.x * 256 + threadIdx.x;
  if (i >= n8) return;
  const float4* p = (const float4*)in + (size_t)i * 2;
  float4 a = p[0], b = p[1];
  s16x8 o;
  o[0] = f2bf(a.x); o[1] = f2bf(a.y); o[2] = f2bf(a.z); o[3] = f2bf(a.w);
  o[4] = f2bf(b.x); o[5] = f2bf(b.y); o[6] = f2bf(b.z); o[7] = f2bf(b.w);
  *(s16x8*)(out + (size_t)i * 8) = o;
}

// ---------- merged weight convert: Wq|Wk|Wv -> wqkv, Wo -> wo ----------
__global__ __launch_bounds__(256) void k_f2bfw(const float* __restrict__ s0,
                                               const float* __restrict__ s1,
                                               const float* __restrict__ s2,
                                               const float* __restrict__ s3,
                                               short* __restrict__ dqkv,
                                               short* __restrict__ dwo) {
  int i = blockIdx.x * 256 + threadIdx.x;  // total n8 = 1310720
  const float* src;
  short* dst;
  if (i < 524288) { src = s0 + (size_t)i * 8; dst = dqkv + (size_t)i * 8; }
  else if (i < 655360) { int j = i - 524288; src = s1 + (size_t)j * 8; dst = dqkv + 4194304 + (size_t)j * 8; }
  else if (i < 786432) { int j = i - 655360; src = s2 + (size_t)j * 8; dst = dqkv + 5242880 + (size_t)j * 8; }
  else { int j = i - 786432; src = s3 + (size_t)j * 8; dst = dwo + (size_t)j * 8; }
  const float4* p = (const float4*)src;
  float4 a = p[0], b = p[1];
  s16x8 o;
  o[0] = f2bf(a.x); o[1] = f2bf(a.y); o[2] = f2bf(a.z); o[3] = f2bf(a.w);
  o[4] = f2bf(b.x); o[5] = f2bf(b.y); o[6] = f2bf(b.z); o[7] = f2bf(b.w);
  *(s16x8*)dst = o;
}

// ---------------- bf16 GEMM: C[M,N] = A[M,K] @ Bw[N,K]^T ----------------
// MODE 1: fp32 row-major C.  MODE 3: fused QKV epilogue.
// XCD-aware bijective block swizzle (T1); requires nwg % 8 == 0.
template <int MODE>
__global__ __launch_bounds__(256) void k_gemm_bt(const short* __restrict__ A,
                                                 const short* __restrict__ Bw,
                                                 void* __restrict__ C,
                                                 void* __restrict__ C2,
                                                 void* __restrict__ C3,
                                                 int M, int N, int K) {
  __shared__ __align__(16) short As[128 * 64];
  __shared__ __align__(16) short Bs[128 * 64];
  const int tid = threadIdx.x;
  const int w = tid >> 6, lane = tid & 63;
  const int wm = w >> 1, wn = w & 1;
  const int nbx = gridDim.x;
  const int f = blockIdx.y * nbx + blockIdx.x;
  const int cpx = (nbx * gridDim.y) >> 3;
  const int sw = (f & 7) * cpx + (f >> 3);
  const int bm = sw / nbx, bn = sw % nbx;
  const int l15 = lane & 15, l4 = lane >> 4;

  f32x4 acc[4][4] = {};

  const int nk = K >> 6;
  for (int kt = 0; kt < nk; ++kt) {
    __syncthreads();
#pragma unroll
    for (int it = 0; it < 4; ++it) {
      int p = it * 256 + tid;
      int p0 = it * 256 + w * 64;
      int r = p >> 3, j = p & 7;
      int jsrc = j ^ (r & 7);
      gload_lds16(A + (size_t)(bm * 128 + r) * K + kt * 64 + jsrc * 8, &As[p0 * 8]);
      gload_lds16(Bw + (size_t)(bn * 128 + r) * K + kt * 64 + jsrc * 8, &Bs[p0 * 8]);
    }
    __syncthreads();
#pragma unroll
    for (int kk = 0; kk < 2; ++kk) {
      s16x8 af[4], bf[4];
      const int jj = kk * 4 + l4;
#pragma unroll
      for (int mi = 0; mi < 4; ++mi) {
        int r = wm * 64 + mi * 16 + l15;
        af[mi] = *(const s16x8*)&As[(r * 8 + (jj ^ (r & 7))) * 8];
      }
#pragma unroll
      for (int ni = 0; ni < 4; ++ni) {
        int r = wn * 64 + ni * 16 + l15;
        bf[ni] = *(const s16x8*)&Bs[(r * 8 + (jj ^ (r & 7))) * 8];
      }
      __builtin_amdgcn_s_setprio(1);
#pragma unroll
      for (int mi = 0; mi < 4; ++mi)
#pragma unroll
        for (int ni = 0; ni < 4; ++ni)
          acc[mi][ni] = __builtin_amdgcn_mfma_f32_16x16x32_bf16(
              af[mi], bf[ni], acc[mi][ni], 0, 0, 0);
      __builtin_amdgcn_s_setprio(0);
    }
  }

#pragma unroll
  for (int mi = 0; mi < 4; ++mi) {
#pragma unroll
    for (int ni = 0; ni < 4; ++ni) {
      int row0 = bm * 128 + wm * 64 + mi * 16 + l4 * 4;
      int col = bn * 128 + wn * 64 + ni * 16 + l15;
      if (MODE == 1) {
        float* Cf = (float*)C;
#pragma unroll
        for (int r2 = 0; r2 < 4; ++r2)
          Cf[(size_t)(row0 + r2) * N + col] = acc[mi][ni][r2];
      } else {  // MODE 3: fused QKV
        if (col < 2048) {
          short* Qo = (short*)C;
#pragma unroll
          for (int r2 = 0; r2 < 4; ++r2)
            Qo[(size_t)(row0 + r2) * 2048 + col] = f2bf(acc[mi][ni][r2]);
        } else if (col < 2560) {
          short* Ko = (short*)C2;
#pragma unroll
          for (int r2 = 0; r2 < 4; ++r2)
            Ko[(size_t)(row0 + r2) * 512 + (col - 2048)] = f2bf(acc[mi][ni][r2]);
        } else {
          short* Vo = (short*)C3;
          int b = row0 >> 11, t0 = row0 & 2047;
          s16x4 pk;
#pragma unroll
          for (int r2 = 0; r2 < 4; ++r2) pk[r2] = f2bf(acc[mi][ni][r2]);
          *(s16x4*)&Vo[(size_t)b * 1048576 + (size_t)(col - 2560) * 2048 + t0] = pk;
        }
      }
    }
  }
}

// ---------------- RoPE in-place on bf16 K ----------------
__global__ __launch_bounds__(256) void k_rope(short* __restrict__ X, int shift,
                                              int rowstride, float mul) {
  int idx = blockIdx.x * 256 + threadIdx.x;
  int row = idx >> shift;
  int rem = idx & ((1 << shift) - 1);
  int h = rem >> 6, d = rem & 63;
  int t = row & 2047;
  float inv = exp2f(-(float)d * (13.287712379549449f / 64.f));
  float ang = (float)t * inv;
  float s, c;
  sincosf(ang, &s, &c);
  size_t base = (size_t)row * rowstride + h * 128 + d;
  float q0 = bf2f(X[base]), q1 = bf2f(X[base + 64]);
  X[base] = f2bf((q0 * c - q1 * s) * mul);
  X[base + 64] = f2bf((q1 * c + q0 * s) * mul);
}

// ---------------- queue counter zero ----------------
__global__ void k_zero(int* p) { if (threadIdx.x == 0) *p = 0; }

// ---------------- flash attention, work-stealing 64-row items ------------
// EXACT round-5 structure (best measured: 86.6 us): K+V LDS dbuf staged via
// gload_lds (rotate layout), 1 barrier/step, parity-split waves, stealing
// with LPT order, merge partials in LDS. Only delta vs round 5: Q RoPE +
// softmax scale folded in-register at Q-load (verified r6-r8), so the
// 16384-block Q-rope kernel is deleted.
__global__ __launch_bounds__(256, 2) void k_attn4(const short* __restrict__ Q,
                                                  const short* __restrict__ Kb,
                                                  const short* __restrict__ Vt,
                                                  short* __restrict__ Y,
                                                  int* __restrict__ qcnt) {
  __shared__ __align__(16) short Ks[2][64 * 128];  // kv-pair rows x 16 chunks
  __shared__ __align__(16) short Vs[2][128 * 64];  // d rows x 8 chunks (64 kv)
  __shared__ int s_item;

  const int tid = threadIdx.x;
  const int w = tid >> 6, lane = tid & 63;
  const int l31 = lane & 31, h5 = lane >> 5;
  const int qc0 = (w >> 1) << 5;  // q-col block: 0 or 32
  const int par = w & 1;          // kv subtile parity

  for (;;) {
    if (tid == 0) s_item = atomicAdd(qcnt, 1);
    __syncthreads();  // also protects LDS reuse across items
    const int item = s_item;
    if (item >= 1024) return;
    const int qi = 31 - (item >> 5);
    const int h = (item >> 1) & 15;
    const int b = item & 1;
    const int kh = h >> 2;
    const int q0 = qi << 6;

    // Q fragments (B-operand): lane = q-col l31, frag f covers d=f*16+h5*8
    s16x8 qf[8];
    const size_t qrow = (size_t)(b * 2048 + q0 + qc0 + l31);
#pragma unroll
    for (int f = 0; f < 8; ++f)
      qf[f] = *(const s16x8*)(Q + qrow * 2048 + h * 128 + f * 16 + h5 * 8);

    // RoPE + softmax scale folded in-register: pair (d, d+64) = qf[f], qf[f+4]
    {
      const float tpos = (float)(q0 + qc0 + l31);
#pragma unroll
      for (int f = 0; f < 4; ++f) {
#pragma unroll
        for (int e = 0; e < 8; ++e) {
          int d = f * 16 + h5 * 8 + e;
          float inv = exp2f((float)d * (-13.287712379549449f / 64.f));
          float sn, cs;
          __sincosf(tpos * inv, &sn, &cs);
          float a = bf2f(qf[f][e]), bv = bf2f(qf[f + 4][e]);
          qf[f][e]     = f2bf((a * cs - bv * sn) * 0.12751758912141852f);
          qf[f + 4][e] = f2bf((bv * cs + a * sn) * 0.12751758912141852f);
        }
      }
    }

    f32x16 oacc[4] = {};
    float m = -1e30f, l = 0.f;

    auto stage = [&](int buf, int t) {
#pragma unroll
      for (int it = 0; it < 4; ++it) {  // K pair: 64 rows x 16 chunks
        int p = it * 256 + tid;
        int p0 = it * 256 + w * 64;
        int r = p >> 4, c = p & 15;
        int csrc = (c - r) & 15;
        gload_lds16(Kb + (size_t)(b * 2048 + t * 64 + r) * 512 + kh * 128 + csrc * 8,
                    &Ks[buf][p0 * 8]);
      }
#pragma unroll
      for (int it = 0; it < 4; ++it) {  // V^T pair: 128 d-rows x 8 chunks
        int p = it * 256 + tid;
        int p0 = it * 256 + w * 64;
        int r = p >> 3, c = p & 7;
        int csrc = (c - r) & 7;
        gload_lds16(Vt + (size_t)b * 1048576 + (size_t)(kh * 128 + r) * 2048 +
                        t * 64 + csrc * 8,
                    &Vs[buf][p0 * 8]);
      }
    };

    stage(0, 0);
    __syncthreads();

    for (int t = 0; t <= qi; ++t) {
      const int cur = t & 1;
      if (t < qi) stage(cur ^ 1, t + 1);

      // diagonal bookkeeping: at t==qi, wave1 (par=1, qcols 0-31) is fully
      // masked -> skip; waves 0 and 3 need the diagonal mask; wave 2 none.
      const bool skipw = (t == qi) && (w == 1);
      if (!skipw) {
        // ---- S^T = K_sub @ Q : lane = q-col, 16 regs = 16 of 32 kv rows ----
        f32x16 sa = {};
        const int kr = par * 32 + l31;
        __builtin_amdgcn_s_setprio(1);
#pragma unroll
        for (int f = 0; f < 8; ++f) {
          int c = f * 2 + h5;
          s16x8 kf = *(const s16x8*)&Ks[cur][(kr * 16 + ((c + kr) & 15)) * 8];
          sa = __builtin_amdgcn_mfma_f32_32x32x16_bf16(kf, qf[f], sa, 0, 0, 0);
        }
        __builtin_amdgcn_s_setprio(0);

        if (t == qi && (w == 0 || w == 3)) {  // diagonal subtile mask
#pragma unroll
          for (int rg = 0; rg < 16; ++rg) {
            int krow = (rg & 3) + 8 * (rg >> 2) + 4 * h5;
            if (krow > l31) sa[rg] = -3.0e38f;
          }
        }

        // ---- online softmax (exp2 domain), 16 regs + h5-partner shfl ----
        float mx[16];
#pragma unroll
        for (int i = 0; i < 16; ++i) mx[i] = sa[i];
#pragma unroll
        for (int stp = 8; stp > 0; stp >>= 1)
#pragma unroll
          for (int i = 0; i < stp; ++i) mx[i] = fmaxf(mx[i], mx[i + stp]);
        float pm = fmaxf(mx[0], __shfl_xor(mx[0], 32));

        if (!__all(pm - m <= 8.f)) {  // defer-max (T13)
          float mn = fmaxf(m, pm);
          float al = exp2f(m - mn);
          m = mn;
          l *= al;
#pragma unroll
          for (int d = 0; d < 4; ++d)
#pragma unroll
            for (int i = 0; i < 16; ++i) oacc[d][i] *= al;
        }

        float sm[16];
#pragma unroll
        for (int i = 0; i < 16; ++i) {
          float e = exp2f(sa[i] - m);
          sa[i] = e;
          sm[i] = e;
        }
#pragma unroll
        for (int stp = 8; stp > 0; stp >>= 1)
#pragma unroll
          for (int i = 0; i < stp; ++i) sm[i] += sm[i + stp];
        l += sm[0] + __shfl_xor(sm[0], 32);

        // ---- P -> bf16 B-operand fragments (in-register relayout) ----
        unsigned u[8], pu[8];
#pragma unroll
        for (int g = 0; g < 4; ++g) {
          u[2 * g]     = cvtpk(sa[4 * g + 0], sa[4 * g + 1]);
          u[2 * g + 1] = cvtpk(sa[4 * g + 2], sa[4 * g + 3]);
        }
#pragma unroll
        for (int g2 = 0; g2 < 8; ++g2) pu[g2] = __shfl_xor(u[g2], 32);
        s16x8 pb[2];
#pragma unroll
        for (int kk = 0; kk < 2; ++kk) {
          union { unsigned uu[4]; s16x8 v; } cv;
          cv.uu[0] = h5 ? pu[4 * kk + 2] : u[4 * kk];
          cv.uu[1] = h5 ? pu[4 * kk + 3] : u[4 * kk + 1];
          cv.uu[2] = h5 ? u[4 * kk + 2]  : pu[4 * kk];
          cv.uu[3] = h5 ? u[4 * kk + 3]  : pu[4 * kk + 1];
          pb[kk] = cv.v;
        }

        // ---- O^T += V_sub^T @ P^T ----
        __builtin_amdgcn_s_setprio(1);
#pragma unroll
        for (int dblk = 0; dblk < 4; ++dblk) {
#pragma unroll
          for (int kk = 0; kk < 2; ++kk) {
            int r = dblk * 32 + l31;
            int c = par * 4 + kk * 2 + h5;
            int slot = (c + r) & 7;
            s16x8 vf = *(const s16x8*)&Vs[cur][(r * 8 + slot) * 8];
            oacc[dblk] = __builtin_amdgcn_mfma_f32_32x32x16_bf16(vf, pb[kk],
                                                                 oacc[dblk], 0, 0, 0);
          }
        }
        __builtin_amdgcn_s_setprio(0);
      }

      __syncthreads();  // buffer handoff + prefetch drain
    }

    // ---- merge parity partials: odd wave writes, even wave merges+stores --
    const int base = (h5 * 32 + l31) * 68;  // 68-float stride, 16B aligned
    if (par) {
      float* mg = (w == 1) ? (float*)&Ks[0][0] : (float*)&Vs[0][0];
#pragma unroll
      for (int d = 0; d < 4; ++d)
#pragma unroll
        for (int rg = 0; rg < 4; ++rg) {
          f32x4 tv;
          tv[0] = oacc[d][rg * 4 + 0];
          tv[1] = oacc[d][rg * 4 + 1];
          tv[2] = oacc[d][rg * 4 + 2];
          tv[3] = oacc[d][rg * 4 + 3];
          *(f32x4*)&mg[base + d * 16 + rg * 4] = tv;
        }
      mg[base + 64] = m;
      mg[base + 65] = l;
    }
    __syncthreads();
    if (!par) {
      const float* mg = (w == 0) ? (const float*)&Ks[0][0] : (const float*)&Vs[0][0];
      float m1 = mg[base + 64], l1 = mg[base + 65];
      float ms = fmaxf(m, m1);
      float a0 = exp2f(m - ms), a1 = exp2f(m1 - ms);
      float li = 1.f / (l * a0 + l1 * a1);
#pragma unroll
      for (int d = 0; d < 4; ++d) {
#pragma unroll
        for (int rg = 0; rg < 4; ++rg) {
          f32x4 po = *(const f32x4*)&mg[base + d * 16 + rg * 4];
          float v0 = (oacc[d][rg * 4 + 0] * a0 + po[0] * a1) * li;
          float v1 = (oacc[d][rg * 4 + 1] * a0 + po[1] * a1) * li;
          float v2 = (oacc[d][rg * 4 + 2] * a0 + po[2] * a1) * li;
          float v3 = (oacc[d][rg * 4 + 3] * a0 + po[3] * a1) * li;
          uint2 st;
          st.x = cvtpk(v0, v1);
          st.y = cvtpk(v2, v3);
          int d0 = d * 32 + 8 * rg + 4 * h5;
          *(uint2*)(Y + qrow * 2048 + h * 128 + d0) = st;
        }
      }
    }
    // next pop's __syncthreads() protects mg/LDS before restaging
  }
}

extern "C" void kernel_launch(void* const* d_in, const int* in_sizes, int n_in,
                              void* d_out, int out_size, void* d_ws, size_t ws_size,
                              hipStream_t stream) {
  (void)in_sizes; (void)n_in; (void)out_size; (void)ws_size;
  const float* x  = (const float*)d_in[0];
  const float* Wq = (const float*)d_in[1];
  const float* Wk = (const float*)d_in[2];
  const float* Wv = (const float*)d_in[3];
  const float* Wo = (const float*)d_in[4];

  char* ws = (char*)d_ws;
  short* xb    = (short*)(ws);              // 4096x2048 bf16 (16 MiB)
  short* wqkvb = (short*)(ws + 16777216);   // 3072x2048      (12 MiB)
  short* wob   = (short*)(ws + 29360128);   // 2048x2048      (8 MiB)
  short* Qb    = (short*)(ws + 37748736);   // 4096x2048      (16 MiB)
  short* Kb    = (short*)(ws + 54525952);   // 4096x512       (4 MiB)
  short* Vtb   = (short*)(ws + 58720256);   // 2x512x2048     (4 MiB)
  short* Yb    = (short*)(ws + 62914560);   // 4096x2048      (16 MiB)
  // queue counter: last 64B of wqkvb (dead after QKV GEMM, rewritten each call)
  int* qcnt    = (int*)(ws + 29360128 - 64);

  k_f2bf<<<4096, 256, 0, stream>>>(x, xb, 1048576);
  k_f2bfw<<<5120, 256, 0, stream>>>(Wq, Wk, Wv, Wo, wqkvb, wob);

  // fused QKV projection: N = 2048(Q) + 512(K) + 512(V) = 3072
  k_gemm_bt<3><<<dim3(24, 32), 256, 0, stream>>>(xb, wqkvb, Qb, Kb, Vtb,
                                                 4096, 3072, 2048);

  // K RoPE only; Q RoPE (+ log2(e)/sqrt(128) scale) is folded into k_attn4
  k_rope<<<4096, 256, 0, stream>>>(Kb, 8, 512, 1.0f);

  k_zero<<<1, 64, 0, stream>>>(qcnt);  // after QKV GEMM consumed wqkvb
  k_attn4<<<512, 256, 0, stream>>>(Qb, Kb, Vtb, Yb, qcnt);

  k_gemm_bt<1><<<dim3(16, 32), 256, 0, stream>>>(Yb, wob, d_out, nullptr,
                                                 nullptr, 4096, 2048, 2048);
}

// Round 11
// 190.216 us; speedup vs baseline: 1.5278x; 1.0183x over previous
//
#include <hip/hip_runtime.h>
#include <hip/hip_bf16.h>

typedef float f32x4 __attribute__((ext_vector_type(4)));
typedef float f32x16 __attribute__((ext_vector_type(16)));
typedef short s16x8 __attribute__((ext_vector_type(8)));
typedef short s16x4 __attribute__((ext_vector_type(4)));

__device__ __forceinline__ short f2bf(float f) {
  union { float f; unsigned u; } v; v.f = f;
  unsigned r = v.u + 0x7fffu + ((v.u >> 16) & 1u);
  return (short)(r >> 16);
}
__device__ __forceinline__ float bf2f(short s) {
  union { unsigned u; float f; } v; v.u = ((unsigned)(unsigned short)s) << 16;
  return v.f;
}
__device__ __forceinline__ unsigned cvtpk(float lo, float hi) {
  unsigned r;
  asm("v_cvt_pk_bf16_f32 %0, %1, %2" : "=v"(r) : "v"(lo), "v"(hi));
  return r;
}

__device__ __forceinline__ void gload_lds16(const short* g, short* l) {
  __builtin_amdgcn_global_load_lds(
      (const __attribute__((address_space(1))) void*)g,
      (__attribute__((address_space(3))) void*)l, 16, 0, 0);
}

// ---- merged convert: x -> xb, Wq|Wk|Wv -> wqkv, Wo -> wo (8 elems/thr) ----
__global__ __launch_bounds__(256) void k_f2bfw(const float* __restrict__ sx,
                                               const float* __restrict__ s0,
                                               const float* __restrict__ s1,
                                               const float* __restrict__ s2,
                                               const float* __restrict__ s3,
                                               short* __restrict__ dx,
                                               short* __restrict__ dqkv,
                                               short* __restrict__ dwo) {
  int i = blockIdx.x * 256 + threadIdx.x;  // total n8 = 2359296
  const float* src;
  short* dst;
  if (i < 1048576) { src = sx + (size_t)i * 8; dst = dx + (size_t)i * 8; }
  else if (i < 1572864) { int j = i - 1048576; src = s0 + (size_t)j * 8; dst = dqkv + (size_t)j * 8; }
  else if (i < 1703936) { int j = i - 1572864; src = s1 + (size_t)j * 8; dst = dqkv + 4194304 + (size_t)j * 8; }
  else if (i < 1835008) { int j = i - 1703936; src = s2 + (size_t)j * 8; dst = dqkv + 5242880 + (size_t)j * 8; }
  else { int j = i - 1835008; src = s3 + (size_t)j * 8; dst = dwo + (size_t)j * 8; }
  const float4* p = (const float4*)src;
  float4 a = p[0], b = p[1];
  s16x8 o;
  o[0] = f2bf(a.x); o[1] = f2bf(a.y); o[2] = f2bf(a.z); o[3] = f2bf(a.w);
  o[4] = f2bf(b.x); o[5] = f2bf(b.y); o[6] = f2bf(b.z); o[7] = f2bf(b.w);
  *(s16x8*)dst = o;
}

// ---------------- bf16 GEMM: C[M,N] = A[M,K] @ Bw[N,K]^T ----------------
// MODE 1: fp32 row-major C.  MODE 3: fused QKV epilogue.
// XCD-aware bijective block swizzle (T1); requires nwg % 8 == 0.
template <int MODE>
__global__ __launch_bounds__(256) void k_gemm_bt(const short* __restrict__ A,
                                                 const short* __restrict__ Bw,
                                                 void* __restrict__ C,
                                                 void* __restrict__ C2,
                                                 void* __restrict__ C3,
                                                 int M, int N, int K) {
  __shared__ __align__(16) short As[128 * 64];
  __shared__ __align__(16) short Bs[128 * 64];
  const int tid = threadIdx.x;
  const int w = tid >> 6, lane = tid & 63;
  const int wm = w >> 1, wn = w & 1;
  const int nbx = gridDim.x;
  const int f = blockIdx.y * nbx + blockIdx.x;
  const int cpx = (nbx * gridDim.y) >> 3;
  const int sw = (f & 7) * cpx + (f >> 3);
  const int bm = sw / nbx, bn = sw % nbx;
  const int l15 = lane & 15, l4 = lane >> 4;

  f32x4 acc[4][4] = {};

  const int nk = K >> 6;
  for (int kt = 0; kt < nk; ++kt) {
    __syncthreads();
#pragma unroll
    for (int it = 0; it < 4; ++it) {
      int p = it * 256 + tid;
      int p0 = it * 256 + w * 64;
      int r = p >> 3, j = p & 7;
      int jsrc = j ^ (r & 7);
      gload_lds16(A + (size_t)(bm * 128 + r) * K + kt * 64 + jsrc * 8, &As[p0 * 8]);
      gload_lds16(Bw + (size_t)(bn * 128 + r) * K + kt * 64 + jsrc * 8, &Bs[p0 * 8]);
    }
    __syncthreads();
#pragma unroll
    for (int kk = 0; kk < 2; ++kk) {
      s16x8 af[4], bf[4];
      const int jj = kk * 4 + l4;
#pragma unroll
      for (int mi = 0; mi < 4; ++mi) {
        int r = wm * 64 + mi * 16 + l15;
        af[mi] = *(const s16x8*)&As[(r * 8 + (jj ^ (r & 7))) * 8];
      }
#pragma unroll
      for (int ni = 0; ni < 4; ++ni) {
        int r = wn * 64 + ni * 16 + l15;
        bf[ni] = *(const s16x8*)&Bs[(r * 8 + (jj ^ (r & 7))) * 8];
      }
      __builtin_amdgcn_s_setprio(1);
#pragma unroll
      for (int mi = 0; mi < 4; ++mi)
#pragma unroll
        for (int ni = 0; ni < 4; ++ni)
          acc[mi][ni] = __builtin_amdgcn_mfma_f32_16x16x32_bf16(
              af[mi], bf[ni], acc[mi][ni], 0, 0, 0);
      __builtin_amdgcn_s_setprio(0);
    }
  }

#pragma unroll
  for (int mi = 0; mi < 4; ++mi) {
#pragma unroll
    for (int ni = 0; ni < 4; ++ni) {
      int row0 = bm * 128 + wm * 64 + mi * 16 + l4 * 4;
      int col = bn * 128 + wn * 64 + ni * 16 + l15;
      if (MODE == 1) {
        float* Cf = (float*)C;
#pragma unroll
        for (int r2 = 0; r2 < 4; ++r2)
          Cf[(size_t)(row0 + r2) * N + col] = acc[mi][ni][r2];
      } else {  // MODE 3: fused QKV
        if (col < 2048) {
          short* Qo = (short*)C;
#pragma unroll
          for (int r2 = 0; r2 < 4; ++r2)
            Qo[(size_t)(row0 + r2) * 2048 + col] = f2bf(acc[mi][ni][r2]);
        } else if (col < 2560) {
          short* Ko = (short*)C2;
#pragma unroll
          for (int r2 = 0; r2 < 4; ++r2)
            Ko[(size_t)(row0 + r2) * 512 + (col - 2048)] = f2bf(acc[mi][ni][r2]);
        } else {
          short* Vo = (short*)C3;
          int b = row0 >> 11, t0 = row0 & 2047;
          s16x4 pk;
#pragma unroll
          for (int r2 = 0; r2 < 4; ++r2) pk[r2] = f2bf(acc[mi][ni][r2]);
          *(s16x4*)&Vo[(size_t)b * 1048576 + (size_t)(col - 2560) * 2048 + t0] = pk;
        }
      }
    }
  }
}

// -------- RoPE in-place on bf16 K; also zeroes the steal counter --------
__global__ __launch_bounds__(256) void k_rope(short* __restrict__ X, int shift,
                                              int rowstride, float mul,
                                              int* __restrict__ qcnt) {
  int idx = blockIdx.x * 256 + threadIdx.x;
  if (idx == 0) *qcnt = 0;  // runs after QKV GEMM consumed wqkvb, before attn
  int row = idx >> shift;
  int rem = idx & ((1 << shift) - 1);
  int h = rem >> 6, d = rem & 63;
  int t = row & 2047;
  float inv = exp2f(-(float)d * (13.287712379549449f / 64.f));
  float ang = (float)t * inv;
  float s, c;
  sincosf(ang, &s, &c);
  size_t base = (size_t)row * rowstride + h * 128 + d;
  float q0 = bf2f(X[base]), q1 = bf2f(X[base + 64]);
  X[base] = f2bf((q0 * c - q1 * s) * mul);
  X[base + 64] = f2bf((q1 * c + q0 * s) * mul);
}

// ---------------- flash attention, work-stealing 64-row items ------------
// EXACT round-5 structure (best measured): K+V LDS dbuf staged via gload_lds
// (rotate layout), 1 barrier/step, parity-split waves, stealing with LPT
// order, merge partials in LDS. Q RoPE + softmax scale folded in-register;
// this round the 32 item-invariant exp2f inv-freqs are hoisted out of the
// item loop (LDS caps occupancy at 2 blocks/CU, so +32 VGPR is free).
__global__ __launch_bounds__(256, 2) void k_attn4(const short* __restrict__ Q,
                                                  const short* __restrict__ Kb,
                                                  const short* __restrict__ Vt,
                                                  short* __restrict__ Y,
                                                  int* __restrict__ qcnt) {
  __shared__ __align__(16) short Ks[2][64 * 128];  // kv-pair rows x 16 chunks
  __shared__ __align__(16) short Vs[2][128 * 64];  // d rows x 8 chunks (64 kv)
  __shared__ int s_item;

  const int tid = threadIdx.x;
  const int w = tid >> 6, lane = tid & 63;
  const int l31 = lane & 31, h5 = lane >> 5;
  const int qc0 = (w >> 1) << 5;  // q-col block: 0 or 32
  const int par = w & 1;          // kv subtile parity

  // item-invariant RoPE inverse frequencies for this lane's 32 d-values
  float invt[32];
#pragma unroll
  for (int f = 0; f < 4; ++f)
#pragma unroll
    for (int e = 0; e < 8; ++e) {
      int d = f * 16 + h5 * 8 + e;
      invt[f * 8 + e] = exp2f((float)d * (-13.287712379549449f / 64.f));
    }

  for (;;) {
    if (tid == 0) s_item = atomicAdd(qcnt, 1);
    __syncthreads();  // also protects LDS reuse across items
    const int item = s_item;
    if (item >= 1024) return;
    const int qi = 31 - (item >> 5);
    const int h = (item >> 1) & 15;
    const int b = item & 1;
    const int kh = h >> 2;
    const int q0 = qi << 6;

    // Q fragments (B-operand): lane = q-col l31, frag f covers d=f*16+h5*8
    s16x8 qf[8];
    const size_t qrow = (size_t)(b * 2048 + q0 + qc0 + l31);
#pragma unroll
    for (int f = 0; f < 8; ++f)
      qf[f] = *(const s16x8*)(Q + qrow * 2048 + h * 128 + f * 16 + h5 * 8);

    // RoPE + softmax scale folded in-register: pair (d, d+64) = qf[f], qf[f+4]
    {
      const float tpos = (float)(q0 + qc0 + l31);
#pragma unroll
      for (int f = 0; f < 4; ++f) {
#pragma unroll
        for (int e = 0; e < 8; ++e) {
          float sn, cs;
          __sincosf(tpos * invt[f * 8 + e], &sn, &cs);
          float a = bf2f(qf[f][e]), bv = bf2f(qf[f + 4][e]);
          qf[f][e]     = f2bf((a * cs - bv * sn) * 0.12751758912141852f);
          qf[f + 4][e] = f2bf((bv * cs + a * sn) * 0.12751758912141852f);
        }
      }
    }

    f32x16 oacc[4] = {};
    float m = -1e30f, l = 0.f;

    auto stage = [&](int buf, int t) {
#pragma unroll
      for (int it = 0; it < 4; ++it) {  // K pair: 64 rows x 16 chunks
        int p = it * 256 + tid;
        int p0 = it * 256 + w * 64;
        int r = p >> 4, c = p & 15;
        int csrc = (c - r) & 15;
        gload_lds16(Kb + (size_t)(b * 2048 + t * 64 + r) * 512 + kh * 128 + csrc * 8,
                    &Ks[buf][p0 * 8]);
      }
#pragma unroll
      for (int it = 0; it < 4; ++it) {  // V^T pair: 128 d-rows x 8 chunks
        int p = it * 256 + tid;
        int p0 = it * 256 + w * 64;
        int r = p >> 3, c = p & 7;
        int csrc = (c - r) & 7;
        gload_lds16(Vt + (size_t)b * 1048576 + (size_t)(kh * 128 + r) * 2048 +
                        t * 64 + csrc * 8,
                    &Vs[buf][p0 * 8]);
      }
    };

    stage(0, 0);
    __syncthreads();

    for (int t = 0; t <= qi; ++t) {
      const int cur = t & 1;
      if (t < qi) stage(cur ^ 1, t + 1);

      // diagonal bookkeeping: at t==qi, wave1 (par=1, qcols 0-31) is fully
      // masked -> skip; waves 0 and 3 need the diagonal mask; wave 2 none.
      const bool skipw = (t == qi) && (w == 1);
      if (!skipw) {
        // ---- S^T = K_sub @ Q : lane = q-col, 16 regs = 16 of 32 kv rows ----
        f32x16 sa = {};
        const int kr = par * 32 + l31;
        __builtin_amdgcn_s_setprio(1);
#pragma unroll
        for (int f = 0; f < 8; ++f) {
          int c = f * 2 + h5;
          s16x8 kf = *(const s16x8*)&Ks[cur][(kr * 16 + ((c + kr) & 15)) * 8];
          sa = __builtin_amdgcn_mfma_f32_32x32x16_bf16(kf, qf[f], sa, 0, 0, 0);
        }
        __builtin_amdgcn_s_setprio(0);

        if (t == qi && (w == 0 || w == 3)) {  // diagonal subtile mask
#pragma unroll
          for (int rg = 0; rg < 16; ++rg) {
            int krow = (rg & 3) + 8 * (rg >> 2) + 4 * h5;
            if (krow > l31) sa[rg] = -3.0e38f;
          }
        }

        // ---- online softmax (exp2 domain), 16 regs + h5-partner shfl ----
        float mx[16];
#pragma unroll
        for (int i = 0; i < 16; ++i) mx[i] = sa[i];
#pragma unroll
        for (int stp = 8; stp > 0; stp >>= 1)
#pragma unroll
          for (int i = 0; i < stp; ++i) mx[i] = fmaxf(mx[i], mx[i + stp]);
        float pm = fmaxf(mx[0], __shfl_xor(mx[0], 32));

        if (!__all(pm - m <= 8.f)) {  // defer-max (T13)
          float mn = fmaxf(m, pm);
          float al = exp2f(m - mn);
          m = mn;
          l *= al;
#pragma unroll
          for (int d = 0; d < 4; ++d)
#pragma unroll
            for (int i = 0; i < 16; ++i) oacc[d][i] *= al;
        }

        float sm[16];
#pragma unroll
        for (int i = 0; i < 16; ++i) {
          float e = exp2f(sa[i] - m);
          sa[i] = e;
          sm[i] = e;
        }
#pragma unroll
        for (int stp = 8; stp > 0; stp >>= 1)
#pragma unroll
          for (int i = 0; i < stp; ++i) sm[i] += sm[i + stp];
        l += sm[0] + __shfl_xor(sm[0], 32);

        // ---- P -> bf16 B-operand fragments (in-register relayout) ----
        unsigned u[8], pu[8];
#pragma unroll
        for (int g = 0; g < 4; ++g) {
          u[2 * g]     = cvtpk(sa[4 * g + 0], sa[4 * g + 1]);
          u[2 * g + 1] = cvtpk(sa[4 * g + 2], sa[4 * g + 3]);
        }
#pragma unroll
        for (int g2 = 0; g2 < 8; ++g2) pu[g2] = __shfl_xor(u[g2], 32);
        s16x8 pb[2];
#pragma unroll
        for (int kk = 0; kk < 2; ++kk) {
          union { unsigned uu[4]; s16x8 v; } cv;
          cv.uu[0] = h5 ? pu[4 * kk + 2] : u[4 * kk];
          cv.uu[1] = h5 ? pu[4 * kk + 3] : u[4 * kk + 1];
          cv.uu[2] = h5 ? u[4 * kk + 2]  : pu[4 * kk];
          cv.uu[3] = h5 ? u[4 * kk + 3]  : pu[4 * kk + 1];
          pb[kk] = cv.v;
        }

        // ---- O^T += V_sub^T @ P^T ----
        __builtin_amdgcn_s_setprio(1);
#pragma unroll
        for (int dblk = 0; dblk < 4; ++dblk) {
#pragma unroll
          for (int kk = 0; kk < 2; ++kk) {
            int r = dblk * 32 + l31;
            int c = par * 4 + kk * 2 + h5;
            int slot = (c + r) & 7;
            s16x8 vf = *(const s16x8*)&Vs[cur][(r * 8 + slot) * 8];
            oacc[dblk] = __builtin_amdgcn_mfma_f32_32x32x16_bf16(vf, pb[kk],
                                                                 oacc[dblk], 0, 0, 0);
          }
        }
        __builtin_amdgcn_s_setprio(0);
      }

      __syncthreads();  // buffer handoff + prefetch drain
    }

    // ---- merge parity partials: odd wave writes, even wave merges+stores --
    const int base = (h5 * 32 + l31) * 68;  // 68-float stride, 16B aligned
    if (par) {
      float* mg = (w == 1) ? (float*)&Ks[0][0] : (float*)&Vs[0][0];
#pragma unroll
      for (int d = 0; d < 4; ++d)
#pragma unroll
        for (int rg = 0; rg < 4; ++rg) {
          f32x4 tv;
          tv[0] = oacc[d][rg * 4 + 0];
          tv[1] = oacc[d][rg * 4 + 1];
          tv[2] = oacc[d][rg * 4 + 2];
          tv[3] = oacc[d][rg * 4 + 3];
          *(f32x4*)&mg[base + d * 16 + rg * 4] = tv;
        }
      mg[base + 64] = m;
      mg[base + 65] = l;
    }
    __syncthreads();
    if (!par) {
      const float* mg = (w == 0) ? (const float*)&Ks[0][0] : (const float*)&Vs[0][0];
      float m1 = mg[base + 64], l1 = mg[base + 65];
      float ms = fmaxf(m, m1);
      float a0 = exp2f(m - ms), a1 = exp2f(m1 - ms);
      float li = 1.f / (l * a0 + l1 * a1);
#pragma unroll
      for (int d = 0; d < 4; ++d) {
#pragma unroll
        for (int rg = 0; rg < 4; ++rg) {
          f32x4 po = *(const f32x4*)&mg[base + d * 16 + rg * 4];
          float v0 = (oacc[d][rg * 4 + 0] * a0 + po[0] * a1) * li;
          float v1 = (oacc[d][rg * 4 + 1] * a0 + po[1] * a1) * li;
          float v2 = (oacc[d][rg * 4 + 2] * a0 + po[2] * a1) * li;
          float v3 = (oacc[d][rg * 4 + 3] * a0 + po[3] * a1) * li;
          uint2 st;
          st.x = cvtpk(v0, v1);
          st.y = cvtpk(v2, v3);
          int d0 = d * 32 + 8 * rg + 4 * h5;
          *(uint2*)(Y + qrow * 2048 + h * 128 + d0) = st;
        }
      }
    }
    // next pop's __syncthreads() protects mg/LDS before restaging
  }
}

extern "C" void kernel_launch(void* const* d_in, const int* in_sizes, int n_in,
                              void* d_out, int out_size, void* d_ws, size_t ws_size,
                              hipStream_t stream) {
  (void)in_sizes; (void)n_in; (void)out_size; (void)ws_size;
  const float* x  = (const float*)d_in[0];
  const float* Wq = (const float*)d_in[1];
  const float* Wk = (const float*)d_in[2];
  const float* Wv = (const float*)d_in[3];
  const float* Wo = (const float*)d_in[4];

  char* ws = (char*)d_ws;
  short* xb    = (short*)(ws);              // 4096x2048 bf16 (16 MiB)
  short* wqkvb = (short*)(ws + 16777216);   // 3072x2048      (12 MiB)
  short* wob   = (short*)(ws + 29360128);   // 2048x2048      (8 MiB)
  short* Qb    = (short*)(ws + 37748736);   // 4096x2048      (16 MiB)
  short* Kb    = (short*)(ws + 54525952);   // 4096x512       (4 MiB)
  short* Vtb   = (short*)(ws + 58720256);   // 2x512x2048     (4 MiB)
  short* Yb    = (short*)(ws + 62914560);   // 4096x2048      (16 MiB)
  // queue counter: last 64B of wqkvb (dead after QKV GEMM; rewritten by
  // k_f2bfw each call, zeroed by k_rope after the GEMM consumed it)
  int* qcnt    = (int*)(ws + 29360128 - 64);

  // one merged convert kernel: x + all weights
  k_f2bfw<<<9216, 256, 0, stream>>>(x, Wq, Wk, Wv, Wo, xb, wqkvb, wob);

  // fused QKV projection: N = 2048(Q) + 512(K) + 512(V) = 3072
  k_gemm_bt<3><<<dim3(24, 32), 256, 0, stream>>>(xb, wqkvb, Qb, Kb, Vtb,
                                                 4096, 3072, 2048);

  // K RoPE (also zeroes qcnt); Q RoPE+scale is folded into k_attn4
  k_rope<<<4096, 256, 0, stream>>>(Kb, 8, 512, 1.0f, qcnt);

  k_attn4<<<512, 256, 0, stream>>>(Qb, Kb, Vtb, Yb, qcnt);

  k_gemm_bt<1><<<dim3(16, 32), 256, 0, stream>>>(Yb, wob, d_out, nullptr,
                                                 nullptr, 4096, 2048, 2048);
}